// Round 5
// baseline (9631.006 us; speedup 1.0000x reference)
//
#include <hip/hip_runtime.h>
#include <hip/hip_cooperative_groups.h>
#include <math.h>

namespace cg = cooperative_groups;

// Problem constants
#define B_    32
#define T_    21
#define STEPS 20
#define V_    10000
#define E_    512
#define A_    512
#define L_    512
#define P_    196
#define ENC_  2048
#define XW_   2560   // E + ENC (x buffer width)
#define ZN_   2048   // 4*L
#define ZCH   14     // z partial chunks: 10 (Wl, K=256) + 4 (Ul, K=128)

// ---- workspace layout (float offsets) ----
#define WS_ORD    0
#define WS_SLEN   32
#define WS_HBUF   64                    // 2*16384 -> 32832
#define WS_CBUF   32832                 // 2*16384 -> 65600
#define WS_ALPHA  65600                 // 6272 -> 71872
#define WS_X      71872                 // 32*2560=81920 -> 153792
#define WS_A1B    153792                // bf16 6272*512 -> +1605632 = 1759424
#define WS_WLB    1759424               // bf16 2560*2048 -> +2621440 = 4380864
#define WS_ULB    4380864               // bf16 512*2048 -> +524288 = 4905152
#define WS_WOB    4905152               // bf16 512*10000 -> +2560000 = 7465152
#define WS_WBB    7465152               // bf16 512*2048 -> +524288 = 7989440
#define WS_WGAB   7989440               // bf16 512*512 -> +131072 = 8120512
#define WS_PZ     8120512               // 14*65536 = 917504 -> 9038016
#define WS_PB     9038016               // 4*65536 = 262144 -> 9300160 (37.2 MB total)
// prologue-only aliases (dead before k_steps runs):
#define WS_MEAN   (WS_PZ)               // 65536
#define WS_PH     (WS_PZ + 65536)       // 524288
#define WS_WEAT   (WS_PZ + 589824)      // 524288 fl = 1048576 bf16

// ---- output layout (float offsets) ----
#define OUT_PRED  0
#define OUT_ALPHA 6400000
#define OUT_ORDER 6525440

typedef __attribute__((ext_vector_type(8))) short bf16x8;
typedef __attribute__((ext_vector_type(4))) float f32x4;
typedef unsigned short ushort_t;

__device__ inline unsigned f2bf2(float lo, float hi) {
    unsigned a = __float_as_uint(lo), b = __float_as_uint(hi);
    a = (a + 0x7FFFu + ((a >> 16) & 1u)) >> 16;
    b = (b + 0x7FFFu + ((b >> 16) & 1u)) >> 16;
    return a | (b << 16);
}
__device__ inline ushort_t f2bf(float f) {
    unsigned u = __float_as_uint(f);
    return (ushort_t)((u + 0x7FFFu + ((u >> 16) & 1u)) >> 16);
}
__device__ inline float bfs(ushort_t u) { return __uint_as_float(((unsigned)u) << 16); }
__device__ inline float bfu_lo(unsigned u) { return __uint_as_float(u << 16); }
__device__ inline float bfu_hi(unsigned u) { return __uint_as_float(u & 0xFFFF0000u); }

// ============ order / lengths ============
__global__ void k_order(const int* __restrict__ seqs, int* __restrict__ ord,
                        int* __restrict__ slen, float* __restrict__ out_ord)
{
    __shared__ int len[B_];
    int i = threadIdx.x;
    if (i < B_) {
        int c = 0;
        for (int t = 0; t < T_; ++t) c += (seqs[i * T_ + t] != 0) ? 1 : 0;
        len[i] = c;
    }
    __syncthreads();
    if (i < B_) {
        int li = len[i], r = 0;
        for (int j = 0; j < B_; ++j) {
            int lj = len[j];
            if (lj > li || (lj == li && j < i)) ++r;
        }
        ord[r]  = i;
        slen[r] = li - 1;
        out_ord[r] = (float)i;
    }
}

// ============ mean-pool encoder (sorted) ============
__global__ void k_mean(const float* __restrict__ enc, const int* __restrict__ ord,
                       float* __restrict__ mean)
{
    int tid = blockIdx.x * 256 + threadIdx.x;
    int b = tid >> 11, e = tid & 2047;
    const float* row = enc + (size_t)ord[b] * (P_ * ENC_) + e;
    float s = 0.f;
    for (int p = 0; p < P_; ++p) s += row[(size_t)p * ENC_];
    mean[tid] = s * (1.0f / 196.0f);
}

// ============ fp32 -> bf16 cast ============
__global__ void k_cast(const float* __restrict__ src, ushort_t* __restrict__ dst, int n)
{
    int i = blockIdx.x * 256 + threadIdx.x;
    if (i < n) dst[i] = f2bf(src[i]);
}

// ============ cast + transpose Wea -> WeaT bf16 [512][2048] ============
__global__ void k_castWT(const float* __restrict__ Wea, ushort_t* __restrict__ WT)
{
    int tid = blockIdx.x * 256 + threadIdx.x;
    int n = tid >> 11, k = tid & 2047;
    WT[tid] = f2bf(Wea[(size_t)k * 512 + n]);
}

// ============ prologue skinny GEMM partial (fp32) ============
__global__ void sg_partial(const float* __restrict__ X, const float* __restrict__ W,
                           float* __restrict__ part, int K, int N, int kchunk, int chunk_ofs)
{
    const int n = blockIdx.x * 256 + threadIdx.x;
    const int c = blockIdx.y;
    const int bh = blockIdx.z;
    const int k0 = c * kchunk;
    int k1 = k0 + kchunk; if (k1 > K) k1 = K;
    float acc[16];
#pragma unroll
    for (int b = 0; b < 16; ++b) acc[b] = 0.f;
    if (n < N) {
        const float* Xb = X + (size_t)(bh * 16) * K;
        for (int k = k0; k < k1; k += 4) {
            float w0 = W[(size_t)(k + 0) * N + n];
            float w1 = W[(size_t)(k + 1) * N + n];
            float w2 = W[(size_t)(k + 2) * N + n];
            float w3 = W[(size_t)(k + 3) * N + n];
#pragma unroll
            for (int b = 0; b < 16; ++b) {
                const float4 xv = *reinterpret_cast<const float4*>(&Xb[(size_t)b * K + k]);
                acc[b] += xv.x * w0 + xv.y * w1 + xv.z * w2 + xv.w * w3;
            }
        }
        float* po = part + (size_t)(chunk_ofs + c) * (B_ * (size_t)N) + (size_t)(bh * 16) * N;
#pragma unroll
        for (int b = 0; b < 16; ++b) po[(size_t)b * N + n] = acc[b];
    }
}

// ============ h0/c0 combine ============
__global__ void k_h0c0(const float* __restrict__ ph, const float* __restrict__ bim,
                       const float* __restrict__ bic, float* __restrict__ h0,
                       float* __restrict__ c0)
{
    int tid = blockIdx.x * 256 + threadIdx.x;
    int half = tid >> 14;
    int idx = tid & 16383;
    int l = idx & 511;
    int cofs = half ? 16 : 0;
    float s = 0.f;
    for (int c = 0; c < 16; ++c) s += ph[(size_t)(cofs + c) * (B_ * 512) + idx];
    if (half) c0[idx] = s + bic[l];
    else      h0[idx] = s + bim[l];
}

// ============ a1 = enc_sorted @ Wea + bea via bf16 MFMA -> bf16 ============
__global__ __launch_bounds__(256, 1) void k_a1_mfma(
    const float* __restrict__ enc, const ushort_t* __restrict__ WeaT,
    const float* __restrict__ bea, const int* __restrict__ ord,
    ushort_t* __restrict__ a1b)
{
    __shared__ ushort_t As[128 * 40];
    __shared__ ushort_t Bs[128 * 40];
    const int tid = threadIdx.x;
    const int lane = tid & 63, wave = tid >> 6;
    const int m0 = blockIdx.x * 128;
    const int n0 = blockIdx.y * 128;

    const int c0 = tid, c1 = tid + 256;
    const int ar0 = c0 >> 2, ak0 = (c0 & 3) * 8;
    const int ar1 = c1 >> 2, ak1 = (c1 & 3) * 8;
    const int g0 = m0 + ar0, g1 = m0 + ar1;
    const float* Ag0 = enc + ((size_t)ord[g0 / P_] * P_ + (g0 % P_)) * ENC_ + ak0;
    const float* Ag1 = enc + ((size_t)ord[g1 / P_] * P_ + (g1 % P_)) * ENC_ + ak1;
    const ushort_t* Bg0 = WeaT + (size_t)(n0 + ar0) * ENC_ + ak0;
    const ushort_t* Bg1 = WeaT + (size_t)(n0 + ar1) * ENC_ + ak1;
    ushort_t* Aw0 = &As[ar0 * 40 + ak0];
    ushort_t* Aw1 = &As[ar1 * 40 + ak1];
    ushort_t* Bw0 = &Bs[ar0 * 40 + ak0];
    ushort_t* Bw1 = &Bs[ar1 * 40 + ak1];

    const int wm = (wave >> 1) * 64, wn = (wave & 1) * 64;
    f32x4 acc[4][4] = {};

    for (int k0i = 0; k0i < ENC_; k0i += 32) {
        float4 v0 = *reinterpret_cast<const float4*>(Ag0 + k0i);
        float4 v1 = *reinterpret_cast<const float4*>(Ag0 + k0i + 4);
        float4 v2 = *reinterpret_cast<const float4*>(Ag1 + k0i);
        float4 v3 = *reinterpret_cast<const float4*>(Ag1 + k0i + 4);
        uint4 pa0, pa1;
        pa0.x = f2bf2(v0.x, v0.y); pa0.y = f2bf2(v0.z, v0.w);
        pa0.z = f2bf2(v1.x, v1.y); pa0.w = f2bf2(v1.z, v1.w);
        pa1.x = f2bf2(v2.x, v2.y); pa1.y = f2bf2(v2.z, v2.w);
        pa1.z = f2bf2(v3.x, v3.y); pa1.w = f2bf2(v3.z, v3.w);
        uint4 pb0 = *reinterpret_cast<const uint4*>(Bg0 + k0i);
        uint4 pb1 = *reinterpret_cast<const uint4*>(Bg1 + k0i);
        __syncthreads();
        *reinterpret_cast<uint4*>(Aw0) = pa0;
        *reinterpret_cast<uint4*>(Aw1) = pa1;
        *reinterpret_cast<uint4*>(Bw0) = pb0;
        *reinterpret_cast<uint4*>(Bw1) = pb1;
        __syncthreads();
        {
            bf16x8 af[4], bfr[4];
            const int arow = wm + (lane & 15);
            const int brow = wn + (lane & 15);
            const int koff = (lane >> 4) * 8;
#pragma unroll
            for (int mt = 0; mt < 4; ++mt)
                af[mt] = *reinterpret_cast<const bf16x8*>(&As[(arow + mt * 16) * 40 + koff]);
#pragma unroll
            for (int nt = 0; nt < 4; ++nt)
                bfr[nt] = *reinterpret_cast<const bf16x8*>(&Bs[(brow + nt * 16) * 40 + koff]);
#pragma unroll
            for (int mt = 0; mt < 4; ++mt)
#pragma unroll
                for (int nt = 0; nt < 4; ++nt)
                    acc[mt][nt] = __builtin_amdgcn_mfma_f32_16x16x32_bf16(
                        af[mt], bfr[nt], acc[mt][nt], 0, 0, 0);
        }
    }
    const int rbase = (lane >> 4) * 4;
    const int cbase = lane & 15;
#pragma unroll
    for (int nt = 0; nt < 4; ++nt) {
        int col = n0 + wn + nt * 16 + cbase;
        float be = bea[col];
#pragma unroll
        for (int mt = 0; mt < 4; ++mt) {
            int row = m0 + wm + mt * 16 + rbase;
#pragma unroll
            for (int r = 0; r < 4; ++r)
                a1b[(size_t)(row + r) * 512 + col] = f2bf(acc[mt][nt][r] + be);
        }
    }
}

// ============ THE persistent cooperative step kernel ============
__global__ __launch_bounds__(256, 1) void k_steps(
    const float* __restrict__ enc, const int* __restrict__ seqs,
    const float* __restrict__ emb,
    const ushort_t* __restrict__ WgaB, const float* __restrict__ bga,
    const float* __restrict__ Wfa, const float* __restrict__ bfa,
    const ushort_t* __restrict__ a1b,
    const ushort_t* __restrict__ WlB, const ushort_t* __restrict__ UlB,
    const float* __restrict__ bl,
    const ushort_t* __restrict__ WbB, const float* __restrict__ bb,
    const ushort_t* __restrict__ WoB, const float* __restrict__ bo,
    const int* __restrict__ ord, const int* __restrict__ slen,
    float* __restrict__ hbuf, float* __restrict__ cbuf,
    float* __restrict__ alpha, float* __restrict__ x,
    float* __restrict__ pz, float* __restrict__ pbuf,
    float* __restrict__ out)
{
    cg::grid_group grid = cg::this_grid();
    const int bid = blockIdx.x;
    const int tid = threadIdx.x;
    const int wave = tid >> 6, lane = tid & 63;
    __shared__ float smem[2528];
    float* cs  = smem;          // 512
    float* a2p = smem + 512;    // 1024
    float* a2s = smem + 1536;   // 512
    float* esh = smem + 2048;   // 224
    float* red = smem + 2272;   // 256

    for (int t = 0; t < STEPS; ++t) {
        const float* h_in = hbuf + (t & 1) * 16384;
        float* h_out      = hbuf + ((t + 1) & 1) * 16384;
        const float* c_in = cbuf + (t & 1) * 16384;
        float* c_out      = cbuf + ((t + 1) & 1) * 16384;

        // ================= Phase A =================
        if (bid < 32) {
            // ---- fused attention for batch b = bid ----
            const int b = bid;
            cs[tid]       = c_in[b * 512 + tid];
            cs[tid + 256] = c_in[b * 512 + 256 + tid];
            __syncthreads();
            {   // a2 = c @ Wga (bf16)
                const int half = tid >> 7, tl = tid & 127;
                const int n4 = tl * 4;
                float4 acc = {0.f, 0.f, 0.f, 0.f};
                const ushort_t* wbase = WgaB + (size_t)(half * 256) * 512 + n4;
                for (int k = 0; k < 256; ++k) {
                    float cv = cs[half * 256 + k];
                    uint2 wr = *reinterpret_cast<const uint2*>(wbase + (size_t)k * 512);
                    acc.x += cv * bfu_lo(wr.x); acc.y += cv * bfu_hi(wr.x);
                    acc.z += cv * bfu_lo(wr.y); acc.w += cv * bfu_hi(wr.y);
                }
                *reinterpret_cast<float4*>(&a2p[half * 512 + n4]) = acc;
            }
            __syncthreads();
            if (tid < 128) {
                const int n4 = tid * 4;
                float4 p0 = *reinterpret_cast<const float4*>(&a2p[n4]);
                float4 p1 = *reinterpret_cast<const float4*>(&a2p[512 + n4]);
                float4 g  = *reinterpret_cast<const float4*>(bga + n4);
                float4 r;
                r.x = p0.x + p1.x + g.x; r.y = p0.y + p1.y + g.y;
                r.z = p0.z + p1.z + g.z; r.w = p0.w + p1.w + g.w;
                *reinterpret_cast<float4*>(&a2s[n4]) = r;
            }
            __syncthreads();
            {   // e[p] = relu(a1[p]+a2) . Wfa
                const int grp = lane >> 4;
                const int sub = lane & 15;
                float4 a2r[4][2], wfr[4][2];
#pragma unroll
                for (int blk = 0; blk < 4; ++blk)
#pragma unroll
                    for (int j = 0; j < 2; ++j) {
                        int d = blk * 128 + sub * 8 + j * 4;
                        a2r[blk][j] = *reinterpret_cast<const float4*>(&a2s[d]);
                        wfr[blk][j] = *reinterpret_cast<const float4*>(Wfa + d);
                    }
                const float bf0 = bfa[0];
                for (int pass = 0; pass < 13; ++pass) {
                    const int p = pass * 16 + wave * 4 + grp;
                    const int pc = p < P_ ? p : P_ - 1;
                    const ushort_t* arow = a1b + ((size_t)b * P_ + pc) * 512;
                    float s = 0.f;
#pragma unroll
                    for (int blk = 0; blk < 4; ++blk) {
                        uint4 raw = *reinterpret_cast<const uint4*>(arow + blk * 128 + sub * 8);
                        float4 av = a2r[blk][0], wv = wfr[blk][0];
                        float v;
                        v = bfu_lo(raw.x) + av.x; v = v > 0.f ? v : 0.f; s += v * wv.x;
                        v = bfu_hi(raw.x) + av.y; v = v > 0.f ? v : 0.f; s += v * wv.y;
                        v = bfu_lo(raw.y) + av.z; v = v > 0.f ? v : 0.f; s += v * wv.z;
                        v = bfu_hi(raw.y) + av.w; v = v > 0.f ? v : 0.f; s += v * wv.w;
                        av = a2r[blk][1]; wv = wfr[blk][1];
                        v = bfu_lo(raw.z) + av.x; v = v > 0.f ? v : 0.f; s += v * wv.x;
                        v = bfu_hi(raw.z) + av.y; v = v > 0.f ? v : 0.f; s += v * wv.y;
                        v = bfu_lo(raw.w) + av.z; v = v > 0.f ? v : 0.f; s += v * wv.z;
                        v = bfu_hi(raw.w) + av.w; v = v > 0.f ? v : 0.f; s += v * wv.w;
                    }
                    s += __shfl_xor(s, 1, 64);
                    s += __shfl_xor(s, 2, 64);
                    s += __shfl_xor(s, 4, 64);
                    s += __shfl_xor(s, 8, 64);
                    if (sub == 0 && p < P_) esh[p] = s + bf0;
                }
            }
            __syncthreads();
            {   // softmax
                float v = (tid < P_) ? esh[tid] : -1e30f;
                red[tid] = v; __syncthreads();
                for (int s2 = 128; s2 > 0; s2 >>= 1) {
                    if (tid < s2) red[tid] = fmaxf(red[tid], red[tid + s2]);
                    __syncthreads();
                }
                float mx = red[0]; __syncthreads();
                float ex = (tid < P_) ? expf(v - mx) : 0.f;
                red[tid] = ex; __syncthreads();
                for (int s2 = 128; s2 > 0; s2 >>= 1) {
                    if (tid < s2) red[tid] += red[tid + s2];
                    __syncthreads();
                }
                float inv = 1.0f / red[0];
                if (tid < P_) {
                    float al = ex * inv;
                    alpha[b * P_ + tid] = al;
                    float mf = (slen[b] > t) ? 1.f : 0.f;
                    out[OUT_ALPHA + ((size_t)b * STEPS + t) * P_ + tid] = al * mf;
                }
            }
        } else if (bid < 96) {
            // ---- Ul partials: pz slots 10..13 ----
            const int task = bid - 32;
            const int c4 = task >> 4, rem = task & 15;
            const int nb = rem >> 1, bh = rem & 1;
            const int n = nb * 256 + tid;
            const int k0 = c4 * 128;
            float acc[16];
#pragma unroll
            for (int b = 0; b < 16; ++b) acc[b] = 0.f;
            const float* Xb = h_in + (size_t)(bh * 16) * 512 + k0;
            const ushort_t* Wp = UlB + (size_t)k0 * 2048 + n;
            for (int kk = 0; kk < 128; kk += 4) {
                float w0 = bfs(Wp[(size_t)(kk + 0) * 2048]);
                float w1 = bfs(Wp[(size_t)(kk + 1) * 2048]);
                float w2 = bfs(Wp[(size_t)(kk + 2) * 2048]);
                float w3 = bfs(Wp[(size_t)(kk + 3) * 2048]);
#pragma unroll
                for (int b = 0; b < 16; ++b) {
                    const float4 xv = *reinterpret_cast<const float4*>(&Xb[(size_t)b * 512 + kk]);
                    acc[b] += xv.x * w0 + xv.y * w1 + xv.z * w2 + xv.w * w3;
                }
            }
            float* po = pz + (size_t)(10 + c4) * 65536 + (size_t)(bh * 16) * 2048 + n;
#pragma unroll
            for (int b = 0; b < 16; ++b) po[(size_t)b * 2048] = acc[b];
        } else if (bid < 160) {
            // ---- Wb partials: pbuf slots 0..3 ----
            const int task = bid - 96;
            const int c4 = task >> 4, rem = task & 15;
            const int nb = rem >> 1, bh = rem & 1;
            const int n = nb * 256 + tid;
            const int k0 = c4 * 128;
            float acc[16];
#pragma unroll
            for (int b = 0; b < 16; ++b) acc[b] = 0.f;
            const float* Xb = c_in + (size_t)(bh * 16) * 512 + k0;
            const ushort_t* Wp = WbB + (size_t)k0 * 2048 + n;
            for (int kk = 0; kk < 128; kk += 4) {
                float w0 = bfs(Wp[(size_t)(kk + 0) * 2048]);
                float w1 = bfs(Wp[(size_t)(kk + 1) * 2048]);
                float w2 = bfs(Wp[(size_t)(kk + 2) * 2048]);
                float w3 = bfs(Wp[(size_t)(kk + 3) * 2048]);
#pragma unroll
                for (int b = 0; b < 16; ++b) {
                    const float4 xv = *reinterpret_cast<const float4*>(&Xb[(size_t)b * 512 + kk]);
                    acc[b] += xv.x * w0 + xv.y * w1 + xv.z * w2 + xv.w * w3;
                }
            }
            float* po = pbuf + (size_t)c4 * 65536 + (size_t)(bh * 16) * 2048 + n;
#pragma unroll
            for (int b = 0; b < 16; ++b) po[(size_t)b * 2048] = acc[b];
        } else if (bid < 224) {
            // ---- emb -> x[:, 0:512] ----
            const int idx = (bid - 160) * 256 + tid;   // 16384
            const int b = idx >> 9, j = idx & 511;
            const int tok = seqs[ord[b] * T_ + t];
            x[b * XW_ + j] = emb[(size_t)tok * E_ + j];
        }
        grid.sync();

        // ================= Phase B: awe * beta -> x[:, 512:2560] =================
        {
            const int b = bid >> 3, ech = bid & 7;
            const int e = ech * 256 + tid;
            const float* erow = enc + (size_t)ord[b] * (P_ * ENC_) + e;
            const float* al = alpha + b * P_;
            float s = 0.f;
            for (int p = 0; p < P_; ++p) s += al[p] * erow[(size_t)p * ENC_];
            float pbsum = pbuf[b * 2048 + e] + pbuf[65536 + b * 2048 + e]
                        + pbuf[2 * 65536 + b * 2048 + e] + pbuf[3 * 65536 + b * 2048 + e];
            float beta = 1.0f / (1.0f + expf(-(pbsum + bb[e])));
            x[b * XW_ + 512 + e] = s * beta;
        }
        grid.sync();

        // ================= Phase C: z partials x@Wl (pz slots 0..9) =================
        if (bid < 160) {
            const int ch = bid >> 4, rem = bid & 15;
            const int nb = rem >> 1, bh = rem & 1;
            const int n = nb * 256 + tid;
            const int k0 = ch * 256;
            float acc[16];
#pragma unroll
            for (int b = 0; b < 16; ++b) acc[b] = 0.f;
            const float* Xb = x + (size_t)(bh * 16) * XW_ + k0;
            const ushort_t* Wp = WlB + (size_t)k0 * 2048 + n;
            for (int kk = 0; kk < 256; kk += 4) {
                float w0 = bfs(Wp[(size_t)(kk + 0) * 2048]);
                float w1 = bfs(Wp[(size_t)(kk + 1) * 2048]);
                float w2 = bfs(Wp[(size_t)(kk + 2) * 2048]);
                float w3 = bfs(Wp[(size_t)(kk + 3) * 2048]);
#pragma unroll
                for (int b = 0; b < 16; ++b) {
                    const float4 xv = *reinterpret_cast<const float4*>(&Xb[(size_t)b * XW_ + kk]);
                    acc[b] += xv.x * w0 + xv.y * w1 + xv.z * w2 + xv.w * w3;
                }
            }
            float* po = pz + (size_t)ch * 65536 + (size_t)(bh * 16) * 2048 + n;
#pragma unroll
            for (int b = 0; b < 16; ++b) po[(size_t)b * 2048] = acc[b];
        }
        grid.sync();

        // ================= Phase D: gates =================
        if (bid < 64) {
            const int idx = bid * 256 + tid;   // 16384
            const int b = idx >> 9, l = idx & 511;
            float zi = 0.f, zf = 0.f, zg = 0.f, zo = 0.f;
            for (int c = 0; c < ZCH; ++c) {
                const float* row = pz + (size_t)c * 65536 + b * 2048;
                zi += row[l]; zf += row[512 + l]; zg += row[1024 + l]; zo += row[1536 + l];
            }
            zi += bl[l]; zf += bl[512 + l]; zg += bl[1024 + l]; zo += bl[1536 + l];
            float si = 1.f / (1.f + expf(-zi));
            float sf = 1.f / (1.f + expf(-zf));
            float so = 1.f / (1.f + expf(-zo));
            float g  = tanhf(zg);
            float cn = sf * c_in[idx] + si * g;
            float hn = so * tanhf(cn);
            float mf = (slen[b] > t) ? 1.f : 0.f;
            c_out[idx] = cn * mf;
            h_out[idx] = hn * mf;
        }
        grid.sync();

        // ================= Phase E: pred = (c_out @ Wo + bo) * mf =================
        if (bid < 160) {
            const int nb = bid >> 2, bq = bid & 3;
            const int n = nb * 256 + tid;
            if (n < V_) {
                float acc[8];
#pragma unroll
                for (int b = 0; b < 8; ++b) acc[b] = 0.f;
                const float* Cb = c_out + (size_t)(bq * 8) * 512;
                const ushort_t* Wp = WoB + n;
                for (int k = 0; k < 512; k += 4) {
                    float w0 = bfs(Wp[(size_t)(k + 0) * V_]);
                    float w1 = bfs(Wp[(size_t)(k + 1) * V_]);
                    float w2 = bfs(Wp[(size_t)(k + 2) * V_]);
                    float w3 = bfs(Wp[(size_t)(k + 3) * V_]);
#pragma unroll
                    for (int b = 0; b < 8; ++b) {
                        const float4 cv = *reinterpret_cast<const float4*>(&Cb[(size_t)b * 512 + k]);
                        acc[b] += cv.x * w0 + cv.y * w1 + cv.z * w2 + cv.w * w3;
                    }
                }
                const float bon = bo[n];
#pragma unroll
                for (int b = 0; b < 8; ++b) {
                    const int gb = bq * 8 + b;
                    float mf = (slen[gb] > t) ? 1.f : 0.f;
                    out[OUT_PRED + ((size_t)gb * STEPS + t) * V_ + n] = (acc[b] + bon) * mf;
                }
            }
        }
        grid.sync();
    }
}

extern "C" void kernel_launch(void* const* d_in, const int* in_sizes, int n_in,
                              void* d_out, int out_size, void* d_ws, size_t ws_size,
                              hipStream_t stream)
{
    const float* enc  = (const float*)d_in[0];
    const int*   seqs = (const int*)  d_in[1];
    const float* emb  = (const float*)d_in[2];
    const float* Wea  = (const float*)d_in[3];
    const float* bea  = (const float*)d_in[4];
    const float* Wga  = (const float*)d_in[5];
    const float* bga  = (const float*)d_in[6];
    const float* Wfa  = (const float*)d_in[7];
    const float* bfa  = (const float*)d_in[8];
    const float* Wl   = (const float*)d_in[9];
    const float* Ul   = (const float*)d_in[10];
    const float* bl   = (const float*)d_in[11];
    const float* Wim  = (const float*)d_in[12];
    const float* bim  = (const float*)d_in[13];
    const float* Wic  = (const float*)d_in[14];
    const float* bic  = (const float*)d_in[15];
    const float* Wb   = (const float*)d_in[16];
    const float* bb   = (const float*)d_in[17];
    const float* Wo   = (const float*)d_in[18];
    const float* bo   = (const float*)d_in[19];

    float* out = (float*)d_out;
    float* ws  = (float*)d_ws;
    int* ord  = (int*)(ws + WS_ORD);
    int* slen = (int*)(ws + WS_SLEN);
    ushort_t* WeaT = (ushort_t*)(ws + WS_WEAT);
    ushort_t* a1b  = (ushort_t*)(ws + WS_A1B);
    ushort_t* WlB  = (ushort_t*)(ws + WS_WLB);
    ushort_t* UlB  = (ushort_t*)(ws + WS_ULB);
    ushort_t* WoB  = (ushort_t*)(ws + WS_WOB);
    ushort_t* WbB  = (ushort_t*)(ws + WS_WBB);
    ushort_t* WgaB = (ushort_t*)(ws + WS_WGAB);

    // ---- prologue ----
    k_order<<<1, 64, 0, stream>>>(seqs, ord, slen, out + OUT_ORDER);
    k_mean<<<256, 256, 0, stream>>>(enc, ord, ws + WS_MEAN);
    sg_partial<<<dim3(2, 16, 2), 256, 0, stream>>>(ws + WS_MEAN, Wim, ws + WS_PH, 2048, 512, 128, 0);
    sg_partial<<<dim3(2, 16, 2), 256, 0, stream>>>(ws + WS_MEAN, Wic, ws + WS_PH, 2048, 512, 128, 16);
    k_h0c0<<<128, 256, 0, stream>>>(ws + WS_PH, bim, bic, ws + WS_HBUF, ws + WS_CBUF);
    k_cast<<<20480, 256, 0, stream>>>(Wl, WlB, 2560 * 2048);
    k_cast<<<4096, 256, 0, stream>>>(Ul, UlB, 512 * 2048);
    k_cast<<<20000, 256, 0, stream>>>(Wo, WoB, 512 * 10000);
    k_cast<<<4096, 256, 0, stream>>>(Wb, WbB, 512 * 2048);
    k_cast<<<1024, 256, 0, stream>>>(Wga, WgaB, 512 * 512);
    k_castWT<<<4096, 256, 0, stream>>>(Wea, WeaT);
    k_a1_mfma<<<dim3(49, 4), 256, 0, stream>>>(enc, WeaT, bea, ord, a1b);

    // ---- all 20 decode steps in ONE cooperative kernel ----
    float* hbuf   = ws + WS_HBUF;
    float* cbuf   = ws + WS_CBUF;
    float* alpha  = ws + WS_ALPHA;
    float* xbuf   = ws + WS_X;
    float* pzbuf  = ws + WS_PZ;
    float* pbbuf  = ws + WS_PB;
    void* args[] = { &enc, &seqs, &emb, &WgaB, &bga, &Wfa, &bfa, &a1b,
                     &WlB, &UlB, &bl, &WbB, &bb, &WoB, &bo,
                     &ord, &slen, &hbuf, &cbuf, &alpha, &xbuf, &pzbuf, &pbbuf, &out };
    hipLaunchCooperativeKernel((const void*)k_steps, dim3(256), dim3(256), args, 0, stream);
}

// Round 7
// 2540.090 us; speedup vs baseline: 3.7916x; 3.7916x over previous
//
#include <hip/hip_runtime.h>
#include <math.h>

#define B_    32
#define T_    21
#define STEPS 20
#define V_    10000
#define E_    512
#define A_    512
#define L_    512
#define P_    196
#define ENC_  2048
#define XW_   2560   // E + ENC
#define ZN_   2048
#define ZCH   14     // pz slots: 10 (x@Wl, K=256 each) + 4 (h@Ul, K=128 each)

// ---- workspace layout (float offsets), total 9,580,608 fl = 38.32 MB ----
#define WS_ORD    0
#define WS_SLEN   32
#define WS_HBUF   64        // 2*16384
#define WS_CBUF   32832     // 2*16384
#define WS_A2S    65600     // 32*512
#define WS_ESH    81984     // 32*256
#define WS_AWEP   90176     // 4*65536
#define WS_X      352320    // 32*2560
#define WS_A1B    434240    // bf16 6272*512  = 3211264 ush -> 1605632 fl
#define WS_WLB    2039872   // bf16 2560*2048 = 5242880 ush -> 2621440 fl
#define WS_ULB    4661312   // bf16 512*2048  = 1048576 ush -> 524288 fl   (was 262144: BUG)
#define WS_WOB    5185600   // bf16 512*10000 = 5120000 ush -> 2560000 fl
#define WS_WBB    7745600   // bf16 512*2048  = 1048576 ush -> 524288 fl   (was 262144: BUG)
#define WS_WGAB   8269888   // bf16 512*512   = 262144 ush  -> 131072 fl
#define WS_PZ     8400960   // 14*65536 = 917504 -> 9318464
#define WS_PB     9318464   // 4*65536 = 262144 -> 9580608
// aliases (lifetimes strictly stream-ordered, no space+time overlap):
#define WS_PP     (WS_PZ)            // 2*320000=640000 <= pz slots 0..9 (655360).
                                     //  gates(t) reads pz BEFORE mega(t) writes pp;
                                     //  predc(t) reads pp BEFORE k_z(t+1) rewrites slots 0..9;
                                     //  Ul partials live in slots 10..13 (>=655360), disjoint.
#define WS_WEAT   (WS_PZ)            // 524288 fl, prologue only (dead after a1; mega-prologue
                                     //  only writes pz slots 10..13 at +655360)
#define WS_MEAN   (WS_PB)            // 65536, prologue only
#define WS_PH     (WS_WBB)           // 524288, prologue only (dead before Wb cast)

// ---- output layout (float offsets) ----
#define OUT_PRED  0
#define OUT_ALPHA 6400000
#define OUT_ORDER 6525440

typedef __attribute__((ext_vector_type(8))) short bf16x8;
typedef __attribute__((ext_vector_type(4))) float f32x4;
typedef unsigned short ushort_t;

__device__ inline unsigned f2bf2(float lo, float hi) {
    unsigned a = __float_as_uint(lo), b = __float_as_uint(hi);
    a = (a + 0x7FFFu + ((a >> 16) & 1u)) >> 16;
    b = (b + 0x7FFFu + ((b >> 16) & 1u)) >> 16;
    return a | (b << 16);
}
__device__ inline ushort_t f2bf(float f) {
    unsigned u = __float_as_uint(f);
    return (ushort_t)((u + 0x7FFFu + ((u >> 16) & 1u)) >> 16);
}
__device__ inline float bfu_lo(unsigned u) { return __uint_as_float(u << 16); }
__device__ inline float bfu_hi(unsigned u) { return __uint_as_float(u & 0xFFFF0000u); }

// ============ order / lengths ============
__global__ void k_order(const int* __restrict__ seqs, int* __restrict__ ord,
                        int* __restrict__ slen, float* __restrict__ out_ord)
{
    __shared__ int len[B_];
    int i = threadIdx.x;
    if (i < B_) {
        int c = 0;
        for (int t = 0; t < T_; ++t) c += (seqs[i * T_ + t] != 0) ? 1 : 0;
        len[i] = c;
    }
    __syncthreads();
    if (i < B_) {
        int li = len[i], r = 0;
        for (int j = 0; j < B_; ++j) {
            int lj = len[j];
            if (lj > li || (lj == li && j < i)) ++r;
        }
        ord[r] = i; slen[r] = li - 1; out_ord[r] = (float)i;
    }
}

// ============ mean-pool encoder (sorted) ============
__global__ void k_mean(const float* __restrict__ enc, const int* __restrict__ ord,
                       float* __restrict__ mean)
{
    int tid = blockIdx.x * 256 + threadIdx.x;
    int b = tid >> 11, e = tid & 2047;
    const float* row = enc + (size_t)ord[b] * (P_ * ENC_) + e;
    float s = 0.f;
    for (int p = 0; p < P_; ++p) s += row[(size_t)p * ENC_];
    mean[tid] = s * (1.0f / 196.0f);
}

// ============ fp32 -> bf16 cast ============
__global__ void k_cast(const float* __restrict__ src, ushort_t* __restrict__ dst, int n)
{
    int i = blockIdx.x * 256 + threadIdx.x;
    if (i < n) dst[i] = f2bf(src[i]);
}

// ============ cast + transpose Wea -> WeaT bf16 [512][2048] ============
__global__ void k_castWT(const float* __restrict__ Wea, ushort_t* __restrict__ WT)
{
    int tid = blockIdx.x * 256 + threadIdx.x;
    int n = tid >> 11, k = tid & 2047;
    WT[tid] = f2bf(Wea[(size_t)k * 512 + n]);
}

// ============ prologue skinny GEMM partial (fp32) for h0/c0 ============
__global__ void sg_partial(const float* __restrict__ X, const float* __restrict__ W,
                           float* __restrict__ part, int K, int N, int kchunk, int chunk_ofs)
{
    const int n = blockIdx.x * 256 + threadIdx.x;
    const int c = blockIdx.y;
    const int bh = blockIdx.z;
    const int k0 = c * kchunk;
    int k1 = k0 + kchunk; if (k1 > K) k1 = K;
    float acc[16];
#pragma unroll
    for (int b = 0; b < 16; ++b) acc[b] = 0.f;
    if (n < N) {
        const float* Xb = X + (size_t)(bh * 16) * K;
        for (int k = k0; k < k1; k += 4) {
            float w0 = W[(size_t)(k + 0) * N + n];
            float w1 = W[(size_t)(k + 1) * N + n];
            float w2 = W[(size_t)(k + 2) * N + n];
            float w3 = W[(size_t)(k + 3) * N + n];
#pragma unroll
            for (int b = 0; b < 16; ++b) {
                const float4 xv = *reinterpret_cast<const float4*>(&Xb[(size_t)b * K + k]);
                acc[b] += xv.x * w0 + xv.y * w1 + xv.z * w2 + xv.w * w3;
            }
        }
        float* po = part + (size_t)(chunk_ofs + c) * (B_ * (size_t)N) + (size_t)(bh * 16) * N;
#pragma unroll
        for (int b = 0; b < 16; ++b) po[(size_t)b * N + n] = acc[b];
    }
}

// ============ h0/c0 combine ============
__global__ void k_h0c0(const float* __restrict__ ph, const float* __restrict__ bim,
                       const float* __restrict__ bic, float* __restrict__ h0,
                       float* __restrict__ c0)
{
    int tid = blockIdx.x * 256 + threadIdx.x;
    int half = tid >> 14;
    int idx = tid & 16383;
    int l = idx & 511;
    int cofs = half ? 16 : 0;
    float s = 0.f;
    for (int c = 0; c < 16; ++c) s += ph[(size_t)(cofs + c) * (B_ * 512) + idx];
    if (half) c0[idx] = s + bic[l];
    else      h0[idx] = s + bim[l];
}

// ============ a1 MFMA, double-buffered LDS pipeline ============
__global__ __launch_bounds__(256, 1) void k_a1_mfma(
    const float* __restrict__ enc, const ushort_t* __restrict__ WeaT,
    const float* __restrict__ bea, const int* __restrict__ ord,
    ushort_t* __restrict__ a1b)
{
    __shared__ ushort_t As[2][128 * 40];
    __shared__ ushort_t Bs[2][128 * 40];
    const int tid = threadIdx.x;
    const int lane = tid & 63, wave = tid >> 6;
    const int m0 = blockIdx.x * 128;
    const int n0 = blockIdx.y * 128;

    const int c0 = tid, c1 = tid + 256;
    const int ar0 = c0 >> 2, ak0 = (c0 & 3) * 8;
    const int ar1 = c1 >> 2, ak1 = (c1 & 3) * 8;
    const int g0 = m0 + ar0, g1 = m0 + ar1;
    const float* Ag0 = enc + ((size_t)ord[g0 / P_] * P_ + (g0 % P_)) * ENC_ + ak0;
    const float* Ag1 = enc + ((size_t)ord[g1 / P_] * P_ + (g1 % P_)) * ENC_ + ak1;
    const ushort_t* Bg0 = WeaT + (size_t)(n0 + ar0) * ENC_ + ak0;
    const ushort_t* Bg1 = WeaT + (size_t)(n0 + ar1) * ENC_ + ak1;
    const int ao0 = ar0 * 40 + ak0, ao1 = ar1 * 40 + ak1;

    const int wm = (wave >> 1) * 64, wn = (wave & 1) * 64;
    f32x4 acc[4][4] = {};

    {
        float4 v0 = *reinterpret_cast<const float4*>(Ag0);
        float4 v1 = *reinterpret_cast<const float4*>(Ag0 + 4);
        float4 v2 = *reinterpret_cast<const float4*>(Ag1);
        float4 v3 = *reinterpret_cast<const float4*>(Ag1 + 4);
        uint4 pa0, pa1;
        pa0.x = f2bf2(v0.x, v0.y); pa0.y = f2bf2(v0.z, v0.w);
        pa0.z = f2bf2(v1.x, v1.y); pa0.w = f2bf2(v1.z, v1.w);
        pa1.x = f2bf2(v2.x, v2.y); pa1.y = f2bf2(v2.z, v2.w);
        pa1.z = f2bf2(v3.x, v3.y); pa1.w = f2bf2(v3.z, v3.w);
        *reinterpret_cast<uint4*>(&As[0][ao0]) = pa0;
        *reinterpret_cast<uint4*>(&As[0][ao1]) = pa1;
        *reinterpret_cast<uint4*>(&Bs[0][ao0]) = *reinterpret_cast<const uint4*>(Bg0);
        *reinterpret_cast<uint4*>(&Bs[0][ao1]) = *reinterpret_cast<const uint4*>(Bg1);
    }
    __syncthreads();

    for (int it = 0; it < 64; ++it) {
        const int cur = it & 1;
        uint4 npa0, npa1, npb0, npb1;
        const bool more = (it < 63);
        if (more) {
            const int k0 = (it + 1) * 32;
            float4 v0 = *reinterpret_cast<const float4*>(Ag0 + k0);
            float4 v1 = *reinterpret_cast<const float4*>(Ag0 + k0 + 4);
            float4 v2 = *reinterpret_cast<const float4*>(Ag1 + k0);
            float4 v3 = *reinterpret_cast<const float4*>(Ag1 + k0 + 4);
            npa0.x = f2bf2(v0.x, v0.y); npa0.y = f2bf2(v0.z, v0.w);
            npa0.z = f2bf2(v1.x, v1.y); npa0.w = f2bf2(v1.z, v1.w);
            npa1.x = f2bf2(v2.x, v2.y); npa1.y = f2bf2(v2.z, v2.w);
            npa1.z = f2bf2(v3.x, v3.y); npa1.w = f2bf2(v3.z, v3.w);
            npb0 = *reinterpret_cast<const uint4*>(Bg0 + k0);
            npb1 = *reinterpret_cast<const uint4*>(Bg1 + k0);
        }
        {
            bf16x8 af[4], bfr[4];
            const int arow = wm + (lane & 15);
            const int brow = wn + (lane & 15);
            const int koff = (lane >> 4) * 8;
#pragma unroll
            for (int mt = 0; mt < 4; ++mt)
                af[mt] = *reinterpret_cast<const bf16x8*>(&As[cur][(arow + mt * 16) * 40 + koff]);
#pragma unroll
            for (int nt = 0; nt < 4; ++nt)
                bfr[nt] = *reinterpret_cast<const bf16x8*>(&Bs[cur][(brow + nt * 16) * 40 + koff]);
#pragma unroll
            for (int mt = 0; mt < 4; ++mt)
#pragma unroll
                for (int nt = 0; nt < 4; ++nt)
                    acc[mt][nt] = __builtin_amdgcn_mfma_f32_16x16x32_bf16(
                        af[mt], bfr[nt], acc[mt][nt], 0, 0, 0);
        }
        if (more) {
            const int nxt = cur ^ 1;
            *reinterpret_cast<uint4*>(&As[nxt][ao0]) = npa0;
            *reinterpret_cast<uint4*>(&As[nxt][ao1]) = npa1;
            *reinterpret_cast<uint4*>(&Bs[nxt][ao0]) = npb0;
            *reinterpret_cast<uint4*>(&Bs[nxt][ao1]) = npb1;
        }
        __syncthreads();
    }
    const int rbase = (lane >> 4) * 4;
    const int cbase = lane & 15;
#pragma unroll
    for (int nt = 0; nt < 4; ++nt) {
        int col = n0 + wn + nt * 16 + cbase;
        float be = bea[col];
#pragma unroll
        for (int mt = 0; mt < 4; ++mt) {
            int row = m0 + wm + mt * 16 + rbase;
#pragma unroll
            for (int r = 0; r < 4; ++r)
                a1b[(size_t)(row + r) * 512 + col] = f2bf(acc[mt][nt][r] + be);
        }
    }
}

// ============ e kernel: 128 blocks (b x 4 p-chunks of 49) ============
__global__ __launch_bounds__(256, 1) void k_e(
    const float* __restrict__ a2s, const float* __restrict__ Wfa,
    const float* __restrict__ bfa, const ushort_t* __restrict__ a1b,
    float* __restrict__ eshW)
{
    __shared__ float a2sh[512];
    __shared__ float wfsh[512];
    const int b = blockIdx.x >> 2, pc = blockIdx.x & 3;
    const int tid = threadIdx.x;
    const int wave = tid >> 6, lane = tid & 63;
    a2sh[tid] = a2s[b * 512 + tid];       a2sh[tid + 256] = a2s[b * 512 + 256 + tid];
    wfsh[tid] = Wfa[tid];                 wfsh[tid + 256] = Wfa[256 + tid];
    __syncthreads();

    const int grp = lane >> 4, sub = lane & 15;
    float4 a2r[4][2], wfr[4][2];
#pragma unroll
    for (int blk = 0; blk < 4; ++blk)
#pragma unroll
        for (int j = 0; j < 2; ++j) {
            int d = blk * 128 + sub * 8 + j * 4;
            a2r[blk][j] = *reinterpret_cast<const float4*>(&a2sh[d]);
            wfr[blk][j] = *reinterpret_cast<const float4*>(&wfsh[d]);
        }
    const float bf0 = bfa[0];
    const int p0 = pc * 49;
#pragma unroll
    for (int pass = 0; pass < 4; ++pass) {
        const int pl = pass * 16 + wave * 4 + grp;
        const bool valid = pl < 49;
        const int p = p0 + (valid ? pl : 0);
        const ushort_t* arow = a1b + ((size_t)b * P_ + p) * 512;
        float s = 0.f;
#pragma unroll
        for (int blk = 0; blk < 4; ++blk) {
            uint4 raw = *reinterpret_cast<const uint4*>(arow + blk * 128 + sub * 8);
            float4 av = a2r[blk][0], wv = wfr[blk][0];
            float v;
            v = bfu_lo(raw.x) + av.x; v = v > 0.f ? v : 0.f; s += v * wv.x;
            v = bfu_hi(raw.x) + av.y; v = v > 0.f ? v : 0.f; s += v * wv.y;
            v = bfu_lo(raw.y) + av.z; v = v > 0.f ? v : 0.f; s += v * wv.z;
            v = bfu_hi(raw.y) + av.w; v = v > 0.f ? v : 0.f; s += v * wv.w;
            av = a2r[blk][1]; wv = wfr[blk][1];
            v = bfu_lo(raw.z) + av.x; v = v > 0.f ? v : 0.f; s += v * wv.x;
            v = bfu_hi(raw.z) + av.y; v = v > 0.f ? v : 0.f; s += v * wv.y;
            v = bfu_lo(raw.w) + av.z; v = v > 0.f ? v : 0.f; s += v * wv.z;
            v = bfu_hi(raw.w) + av.w; v = v > 0.f ? v : 0.f; s += v * wv.w;
        }
        s += __shfl_xor(s, 1, 64);
        s += __shfl_xor(s, 2, 64);
        s += __shfl_xor(s, 4, 64);
        s += __shfl_xor(s, 8, 64);
        if (sub == 0 && valid) eshW[b * 256 + p0 + pl] = s + bf0;
    }
}

// ============ softmax(recompute) + awe partial + out_alpha: 128 blocks ============
__global__ __launch_bounds__(256, 1) void k_awe_sm(
    const float* __restrict__ eshW, const float* __restrict__ enc,
    const int* __restrict__ ord, const int* __restrict__ slen, int t,
    float* __restrict__ awep, float* __restrict__ out_alpha)
{
    __shared__ float red[256];
    __shared__ float alsh[49];
    const int b = blockIdx.x >> 2, ph = blockIdx.x & 3;
    const int tid = threadIdx.x;
    const int p0 = ph * 49;

    float v = (tid < P_) ? eshW[b * 256 + tid] : -1e30f;
    red[tid] = v; __syncthreads();
    for (int s2 = 128; s2 > 0; s2 >>= 1) {
        if (tid < s2) red[tid] = fmaxf(red[tid], red[tid + s2]);
        __syncthreads();
    }
    float mx = red[0]; __syncthreads();
    float ex = (tid < P_) ? expf(v - mx) : 0.f;
    red[tid] = ex; __syncthreads();
    for (int s2 = 128; s2 > 0; s2 >>= 1) {
        if (tid < s2) red[tid] += red[tid + s2];
        __syncthreads();
    }
    float inv = 1.0f / red[0];
    if (ph == 0 && tid < P_) {
        float mf = (slen[b] > t) ? 1.f : 0.f;
        out_alpha[((size_t)b * STEPS + t) * P_ + tid] = ex * inv * mf;
    }
    if (tid < 49) alsh[tid] = expf(eshW[b * 256 + p0 + tid] - mx) * inv;
    __syncthreads();

    const int e0 = tid * 8;
    const float* erow = enc + (size_t)ord[b] * (P_ * ENC_) + (size_t)p0 * ENC_ + e0;
    float4 s0 = {0.f, 0.f, 0.f, 0.f}, s1 = {0.f, 0.f, 0.f, 0.f};
    for (int i = 0; i < 49; ++i) {
        float ap = alsh[i];
        float4 u0 = *reinterpret_cast<const float4*>(erow + (size_t)i * ENC_);
        float4 u1 = *reinterpret_cast<const float4*>(erow + (size_t)i * ENC_ + 4);
        s0.x += ap * u0.x; s0.y += ap * u0.y; s0.z += ap * u0.z; s0.w += ap * u0.w;
        s1.x += ap * u1.x; s1.y += ap * u1.y; s1.z += ap * u1.z; s1.w += ap * u1.w;
    }
    float* po = awep + (size_t)ph * 65536 + b * 2048 + e0;
    *reinterpret_cast<float4*>(po) = s0;
    *reinterpret_cast<float4*>(po + 4) = s1;
}

// ============ buildx: combine awe partials + beta -> x[:,512:2560] ============
__global__ void k_buildx(const float* __restrict__ awep, const float* __restrict__ pb,
                         const float* __restrict__ bb, float* __restrict__ x)
{
    const int b = blockIdx.x;
    const int e0 = threadIdx.x * 8;
    float s[8] = {0,0,0,0,0,0,0,0}, pbs[8] = {0,0,0,0,0,0,0,0};
#pragma unroll
    for (int sl = 0; sl < 4; ++sl) {
        const float* ap = awep + (size_t)sl * 65536 + b * 2048 + e0;
        const float* pp = pb   + (size_t)sl * 65536 + b * 2048 + e0;
#pragma unroll
        for (int j = 0; j < 8; ++j) { s[j] += ap[j]; pbs[j] += pp[j]; }
    }
    float* xo = x + (size_t)b * XW_ + 512 + e0;
#pragma unroll
    for (int j = 0; j < 8; ++j) {
        float beta = 1.0f / (1.0f + expf(-(pbs[j] + bb[e0 + j])));
        xo[j] = s[j] * beta;
    }
}

// ============ z partials: x @ Wl, grid (4,10,2) ============
__global__ void k_z(const float* __restrict__ x, const ushort_t* __restrict__ WlB,
                    float* __restrict__ pz)
{
    const int n0 = (blockIdx.x * 256 + threadIdx.x) * 2;
    const int ch = blockIdx.y;
    const int bh = blockIdx.z;
    const int k0 = ch * 256;
    float acc[16][2];
#pragma unroll
    for (int b = 0; b < 16; ++b) { acc[b][0] = 0.f; acc[b][1] = 0.f; }
    const float* Xb = x + (size_t)(bh * 16) * XW_ + k0;
    const ushort_t* Wp = WlB + (size_t)k0 * ZN_ + n0;
    for (int kk = 0; kk < 256; kk += 4) {
        unsigned w0 = *reinterpret_cast<const unsigned*>(Wp + (size_t)(kk + 0) * ZN_);
        unsigned w1 = *reinterpret_cast<const unsigned*>(Wp + (size_t)(kk + 1) * ZN_);
        unsigned w2 = *reinterpret_cast<const unsigned*>(Wp + (size_t)(kk + 2) * ZN_);
        unsigned w3 = *reinterpret_cast<const unsigned*>(Wp + (size_t)(kk + 3) * ZN_);
        float l0 = bfu_lo(w0), h0 = bfu_hi(w0), l1 = bfu_lo(w1), h1 = bfu_hi(w1);
        float l2 = bfu_lo(w2), h2 = bfu_hi(w2), l3 = bfu_lo(w3), h3 = bfu_hi(w3);
#pragma unroll
        for (int b = 0; b < 16; ++b) {
            const float4 xv = *reinterpret_cast<const float4*>(&Xb[(size_t)b * XW_ + kk]);
            acc[b][0] += xv.x * l0 + xv.y * l1 + xv.z * l2 + xv.w * l3;
            acc[b][1] += xv.x * h0 + xv.y * h1 + xv.z * h2 + xv.w * h3;
        }
    }
    float* po = pz + (size_t)ch * 65536 + (size_t)(bh * 16) * ZN_ + n0;
#pragma unroll
    for (int b = 0; b < 16; ++b) {
        po[(size_t)b * ZN_ + 0] = acc[b][0];
        po[(size_t)b * ZN_ + 1] = acc[b][1];
    }
}

// ============ gates ============
__global__ void k_gates(const float* __restrict__ pz, const float* __restrict__ bl,
                        const float* __restrict__ c_in, const int* __restrict__ slen, int t,
                        float* __restrict__ c_out, float* __restrict__ h_out)
{
    int tid = blockIdx.x * 256 + threadIdx.x;
    int b = tid >> 9, l = tid & 511;
    float zi = 0.f, zf = 0.f, zg = 0.f, zo = 0.f;
    for (int c = 0; c < ZCH; ++c) {
        const float* row = pz + (size_t)c * 65536 + b * ZN_;
        zi += row[l]; zf += row[512 + l]; zg += row[1024 + l]; zo += row[1536 + l];
    }
    zi += bl[l]; zf += bl[512 + l]; zg += bl[1024 + l]; zo += bl[1536 + l];
    float si = 1.f / (1.f + expf(-zi));
    float sf = 1.f / (1.f + expf(-zf));
    float so = 1.f / (1.f + expf(-zo));
    float g  = tanhf(zg);
    float cn = sf * c_in[tid] + si * g;
    float hn = so * tanhf(cn);
    float mf = (slen[b] > t) ? 1.f : 0.f;
    c_out[tid] = cn * mf;
    h_out[tid] = hn * mf;
}

// ============ mega: Wo partials (step t) + prep for step tnext ============
// bids: 0..79 Wo | 80..111 a2 | 112..143 Wb | 144..175 Ul | 176..183 emb
__global__ void k_mega(int do_wo, int tnext,
                       const float* __restrict__ cptr, const float* __restrict__ hptr,
                       const int* __restrict__ seqs, const float* __restrict__ emb,
                       const int* __restrict__ ord,
                       const ushort_t* __restrict__ WoB,
                       const ushort_t* __restrict__ WgaB, const float* __restrict__ bga,
                       const ushort_t* __restrict__ WbB, const ushort_t* __restrict__ UlB,
                       float* __restrict__ a2s, float* __restrict__ x,
                       float* __restrict__ pb, float* __restrict__ pz,
                       float* __restrict__ pp)
{
    const int bid = blockIdx.x;
    const int tid = threadIdx.x;
    if (bid < 80) {
        if (!do_wo) return;
        const int kcb = bid & 1, bh = (bid >> 1) & 1, nb = bid >> 2;
        const int n0 = (nb * 256 + tid) * 2;
        if (n0 >= V_) return;
        const int k0 = kcb * 256;
        float acc[16][2];
#pragma unroll
        for (int b = 0; b < 16; ++b) { acc[b][0] = 0.f; acc[b][1] = 0.f; }
        const float* Xb = cptr + (size_t)(bh * 16) * 512 + k0;
        const ushort_t* Wp = WoB + (size_t)k0 * V_ + n0;
        for (int kk = 0; kk < 256; kk += 4) {
            unsigned w0 = *reinterpret_cast<const unsigned*>(Wp + (size_t)(kk + 0) * V_);
            unsigned w1 = *reinterpret_cast<const unsigned*>(Wp + (size_t)(kk + 1) * V_);
            unsigned w2 = *reinterpret_cast<const unsigned*>(Wp + (size_t)(kk + 2) * V_);
            unsigned w3 = *reinterpret_cast<const unsigned*>(Wp + (size_t)(kk + 3) * V_);
            float l0 = bfu_lo(w0), h0 = bfu_hi(w0), l1 = bfu_lo(w1), h1 = bfu_hi(w1);
            float l2 = bfu_lo(w2), h2 = bfu_hi(w2), l3 = bfu_lo(w3), h3 = bfu_hi(w3);
#pragma unroll
            for (int b = 0; b < 16; ++b) {
                const float4 cv = *reinterpret_cast<const float4*>(&Xb[(size_t)b * 512 + kk]);
                acc[b][0] += cv.x * l0 + cv.y * l1 + cv.z * l2 + cv.w * l3;
                acc[b][1] += cv.x * h0 + cv.y * h1 + cv.z * h2 + cv.w * h3;
            }
        }
        float* po = pp + (size_t)kcb * 320000 + (size_t)(bh * 16) * V_ + n0;
#pragma unroll
        for (int b = 0; b < 16; ++b) {
            po[(size_t)b * V_ + 0] = acc[b][0];
            po[(size_t)b * V_ + 1] = acc[b][1];
        }
    } else if (bid < 112) {
        __shared__ float cs[512];
        __shared__ float a2p[2][512];
        const int b = bid - 80;
        cs[tid] = cptr[b * 512 + tid]; cs[tid + 256] = cptr[b * 512 + 256 + tid];
        __syncthreads();
        const int half = tid >> 7, tl = tid & 127;
        const int n4 = tl * 4;
        float4 acc = {0.f, 0.f, 0.f, 0.f};
        const ushort_t* wbase = WgaB + (size_t)(half * 256) * 512 + n4;
        for (int k = 0; k < 256; ++k) {
            float cv = cs[half * 256 + k];
            uint2 wr = *reinterpret_cast<const uint2*>(wbase + (size_t)k * 512);
            acc.x += cv * bfu_lo(wr.x); acc.y += cv * bfu_hi(wr.x);
            acc.z += cv * bfu_lo(wr.y); acc.w += cv * bfu_hi(wr.y);
        }
        *reinterpret_cast<float4*>(&a2p[half][n4]) = acc;
        __syncthreads();
        if (tid < 128) {
            const int n44 = tid * 4;
            float4 p0 = *reinterpret_cast<const float4*>(&a2p[0][n44]);
            float4 p1 = *reinterpret_cast<const float4*>(&a2p[1][n44]);
            float4 g  = *reinterpret_cast<const float4*>(bga + n44);
            float4 r;
            r.x = p0.x + p1.x + g.x; r.y = p0.y + p1.y + g.y;
            r.z = p0.z + p1.z + g.z; r.w = p0.w + p1.w + g.w;
            *reinterpret_cast<float4*>(&a2s[b * 512 + n44]) = r;
        }
    } else if (bid < 176) {
        const bool isUl = (bid >= 144);
        const int idx = bid - (isUl ? 144 : 112);
        const int kcb = idx & 3, bh = (idx >> 2) & 1, nb = idx >> 3;
        const int n0 = (nb * 256 + tid) * 2;
        const int k0 = kcb * 128;
        const float* Xb = (isUl ? hptr : cptr) + (size_t)(bh * 16) * 512 + k0;
        const ushort_t* Wp = (isUl ? UlB : WbB) + (size_t)k0 * ZN_ + n0;
        float acc[16][2];
#pragma unroll
        for (int b = 0; b < 16; ++b) { acc[b][0] = 0.f; acc[b][1] = 0.f; }
        for (int kk = 0; kk < 128; kk += 4) {
            unsigned w0 = *reinterpret_cast<const unsigned*>(Wp + (size_t)(kk + 0) * ZN_);
            unsigned w1 = *reinterpret_cast<const unsigned*>(Wp + (size_t)(kk + 1) * ZN_);
            unsigned w2 = *reinterpret_cast<const unsigned*>(Wp + (size_t)(kk + 2) * ZN_);
            unsigned w3 = *reinterpret_cast<const unsigned*>(Wp + (size_t)(kk + 3) * ZN_);
            float l0 = bfu_lo(w0), h0 = bfu_hi(w0), l1 = bfu_lo(w1), h1 = bfu_hi(w1);
            float l2 = bfu_lo(w2), h2 = bfu_hi(w2), l3 = bfu_lo(w3), h3 = bfu_hi(w3);
#pragma unroll
            for (int b = 0; b < 16; ++b) {
                const float4 xv = *reinterpret_cast<const float4*>(&Xb[(size_t)b * 512 + kk]);
                acc[b][0] += xv.x * l0 + xv.y * l1 + xv.z * l2 + xv.w * l3;
                acc[b][1] += xv.x * h0 + xv.y * h1 + xv.z * h2 + xv.w * h3;
            }
        }
        float* po = (isUl ? (pz + (size_t)(10 + kcb) * 65536) : (pb + (size_t)kcb * 65536))
                    + (size_t)(bh * 16) * ZN_ + n0;
#pragma unroll
        for (int b = 0; b < 16; ++b) {
            po[(size_t)b * ZN_ + 0] = acc[b][0];
            po[(size_t)b * ZN_ + 1] = acc[b][1];
        }
    } else {
        const int g = (bid - 176) * 256 + tid;     // 0..2047
        const int b = g >> 6, j0 = (g & 63) * 8;
        const int tok = seqs[ord[b] * T_ + tnext];
        const float4* src = reinterpret_cast<const float4*>(emb + (size_t)tok * E_ + j0);
        float4* dst = reinterpret_cast<float4*>(x + (size_t)b * XW_ + j0);
        dst[0] = src[0]; dst[1] = src[1];
    }
}

// ============ pred combine (2 pp slots) ============
__global__ void k_predc(const float* __restrict__ pp, const float* __restrict__ bo,
                        const int* __restrict__ slen, int t, float* __restrict__ out)
{
    int tid = blockIdx.x * 256 + threadIdx.x;
    if (tid >= B_ * V_) return;
    int b = tid / V_, v = tid - b * V_;
    float s = pp[tid] + pp[320000 + tid] + bo[v];
    float mf = (slen[b] > t) ? 1.f : 0.f;
    out[((size_t)b * STEPS + t) * V_ + v] = s * mf;
}

extern "C" void kernel_launch(void* const* d_in, const int* in_sizes, int n_in,
                              void* d_out, int out_size, void* d_ws, size_t ws_size,
                              hipStream_t stream)
{
    const float* enc  = (const float*)d_in[0];
    const int*   seqs = (const int*)  d_in[1];
    const float* emb  = (const float*)d_in[2];
    const float* Wea  = (const float*)d_in[3];
    const float* bea  = (const float*)d_in[4];
    const float* Wga  = (const float*)d_in[5];
    const float* bga  = (const float*)d_in[6];
    const float* Wfa  = (const float*)d_in[7];
    const float* bfa  = (const float*)d_in[8];
    const float* Wl   = (const float*)d_in[9];
    const float* Ul   = (const float*)d_in[10];
    const float* bl   = (const float*)d_in[11];
    const float* Wim  = (const float*)d_in[12];
    const float* bim  = (const float*)d_in[13];
    const float* Wic  = (const float*)d_in[14];
    const float* bic  = (const float*)d_in[15];
    const float* Wb   = (const float*)d_in[16];
    const float* bb   = (const float*)d_in[17];
    const float* Wo   = (const float*)d_in[18];
    const float* bo   = (const float*)d_in[19];

    float* out = (float*)d_out;
    float* ws  = (float*)d_ws;
    int* ord  = (int*)(ws + WS_ORD);
    int* slen = (int*)(ws + WS_SLEN);
    ushort_t* WeaT = (ushort_t*)(ws + WS_WEAT);
    ushort_t* a1b  = (ushort_t*)(ws + WS_A1B);
    ushort_t* WlB  = (ushort_t*)(ws + WS_WLB);
    ushort_t* UlB  = (ushort_t*)(ws + WS_ULB);
    ushort_t* WoB  = (ushort_t*)(ws + WS_WOB);
    ushort_t* WbB  = (ushort_t*)(ws + WS_WBB);
    ushort_t* WgaB = (ushort_t*)(ws + WS_WGAB);
    float* a2s  = ws + WS_A2S;
    float* eshW = ws + WS_ESH;
    float* awep = ws + WS_AWEP;
    float* xbuf = ws + WS_X;
    float* pz   = ws + WS_PZ;
    float* pb   = ws + WS_PB;
    float* pp   = ws + WS_PP;

    // ---- prologue ----
    k_order<<<1, 64, 0, stream>>>(seqs, ord, slen, out + OUT_ORDER);
    k_mean<<<256, 256, 0, stream>>>(enc, ord, ws + WS_MEAN);
    sg_partial<<<dim3(2, 16, 2), 256, 0, stream>>>(ws + WS_MEAN, Wim, ws + WS_PH, 2048, 512, 128, 0);
    sg_partial<<<dim3(2, 16, 2), 256, 0, stream>>>(ws + WS_MEAN, Wic, ws + WS_PH, 2048, 512, 128, 16);
    k_h0c0<<<128, 256, 0, stream>>>(ws + WS_PH, bim, bic, ws + WS_HBUF, ws + WS_CBUF);
    k_cast<<<20480, 256, 0, stream>>>(Wl, WlB, 2560 * 2048);
    k_cast<<<4096, 256, 0, stream>>>(Ul, UlB, 512 * 2048);
    k_cast<<<20000, 256, 0, stream>>>(Wo, WoB, 512 * 10000);
    k_cast<<<4096, 256, 0, stream>>>(Wb, WbB, 512 * 2048);
    k_cast<<<1024, 256, 0, stream>>>(Wga, WgaB, 512 * 512);
    k_castWT<<<4096, 256, 0, stream>>>(Wea, WeaT);
    k_a1_mfma<<<dim3(49, 4), 256, 0, stream>>>(enc, WeaT, bea, ord, a1b);
    // prep for step 0 (a2, Wb, Ul, emb from h0/c0); Wo branch disabled
    k_mega<<<184, 256, 0, stream>>>(0, 0, ws + WS_CBUF, ws + WS_HBUF, seqs, emb, ord,
                                    WoB, WgaB, bga, WbB, UlB, a2s, xbuf, pb, pz, pp);

    // ---- decode steps ----
    for (int t = 0; t < STEPS; ++t) {
        float* h_in  = ws + WS_HBUF + (t & 1) * (B_ * L_);
        float* h_out = ws + WS_HBUF + ((t + 1) & 1) * (B_ * L_);
        float* c_in  = ws + WS_CBUF + (t & 1) * (B_ * L_);
        float* c_out = ws + WS_CBUF + ((t + 1) & 1) * (B_ * L_);
        (void)h_in;

        k_e<<<128, 256, 0, stream>>>(a2s, Wfa, bfa, a1b, eshW);
        k_awe_sm<<<128, 256, 0, stream>>>(eshW, enc, ord, slen, t, awep, out + OUT_ALPHA);
        k_buildx<<<32, 256, 0, stream>>>(awep, pb, bb, xbuf);
        k_z<<<dim3(4, 10, 2), 256, 0, stream>>>(xbuf, WlB, pz);
        k_gates<<<64, 256, 0, stream>>>(pz, bl, c_in, slen, t, c_out, h_out);
        k_mega<<<184, 256, 0, stream>>>(1, t + 1, c_out, h_out, seqs, emb, ord,
                                        WoB, WgaB, bga, WbB, UlB, a2s, xbuf, pb, pz, pp);
        k_predc<<<1250, 256, 0, stream>>>(pp, bo, slen, t, out + OUT_PRED);
    }
}